// Round 1
// baseline (115.876 us; speedup 1.0000x reference)
//
#include <hip/hip_runtime.h>

// Problem constants (from reference): NI=128, NS=8, D=4, W=H=72, RADIUS=5
#define WDIM 72
#define WH   (72 * 72)       // 5184
#define RAD  5
#define NOFF 121             // (2R+1)^2

// One block per batch element b (B = NI*NS = 1024).
// Phase 1: fill this b's output plane (5184 floats) with -1.0 via float4.
// Phase 2: lanes 0..120 each own one (rw, rh) offset. The JAX scan writes
// offsets in order t = (rw+5)*11 + (rh+5), last-write-wins on collisions
// (which only occur under clipping). Since clipped cw depends only on rw and
// clipped ch only on rh, the winning lane for a cell is exactly the lane with
// the largest rw mapping to its cw AND largest rh mapping to its ch:
//   win_axis = (r == RAD) || (0 <= c + r <= WDIM-2)
// (if c+r >= WDIM-1, the next r clips to the same WDIM-1; if c+r <= -1, the
//  next r clips to the same 0). Winners have unique cells -> no race.
__global__ __launch_bounds__(128) void iou_label_kernel(
    const float* __restrict__ outp,   // (B, 4, 72, 72)
    const int*   __restrict__ ind,    // (B,)
    const float* __restrict__ target, // (B, 4)
    float*       __restrict__ dst)    // (B, 72, 72)
{
    const int b = blockIdx.x;
    const int t = threadIdx.x;

    float* plane = dst + (size_t)b * WH;

    // ---- Phase 1: fill plane with -1.0f (1296 float4 stores / block) ----
    float4 neg1 = make_float4(-1.f, -1.f, -1.f, -1.f);
    float4* p4 = reinterpret_cast<float4*>(plane);
    #pragma unroll
    for (int i = t; i < WH / 4; i += 128) p4[i] = neg1;
    __syncthreads();

    // ---- Phase 2: scatter IoU for winning offsets ----
    if (t >= NOFF) return;

    const int rw = t / 11 - RAD;   // slow index (matches jnp.repeat)
    const int rh = t % 11 - RAD;   // fast index (matches jnp.tile)

    const int idx = ind[b];
    const int cw = idx % WDIM;
    const int ch = idx / WDIM;

    const int hh = ch + rh;
    const int ww = cw + rw;
    const bool winh = (rh == RAD) || (hh >= 0 && hh <= WDIM - 2);
    const bool winw = (rw == RAD) || (ww >= 0 && ww <= WDIM - 2);
    if (!(winh && winw)) return;

    const int chc = min(max(hh, 0), WDIM - 1);
    const int cwc = min(max(ww, 0), WDIM - 1);
    const int ic  = chc * WDIM + cwc;

    // pred[d] = outp[b, d, chc, cwc]  (stride WH between d-planes)
    const float* ob = outp + (size_t)b * 4 * WH + ic;
    const float pl = ob[0 * WH];
    const float pr = ob[1 * WH];
    const float pt = ob[2 * WH];
    const float pb = ob[3 * WH];

    const float4 tg = *reinterpret_cast<const float4*>(target + (size_t)b * 4);
    const float frw = (float)rw, frh = (float)rh;
    const float tl = tg.x + frw;
    const float tr = tg.y - frw;
    const float tt = tg.z + frh;
    const float tb = tg.w - frh;

    const float inter = (fminf(pl, tl) + fminf(pr, tr)) *
                        (fminf(pb, tb) + fminf(pt, tt));
    const float uni   = (tl + tr) * (tt + tb) + (pl + pr) * (pt + pb) - inter;

    plane[ic] = (inter + 1.0f) / (uni + 1.0f);
}

extern "C" void kernel_launch(void* const* d_in, const int* in_sizes, int n_in,
                              void* d_out, int out_size, void* d_ws, size_t ws_size,
                              hipStream_t stream) {
    const float* outp   = (const float*)d_in[0]; // (128,8,4,72,72)
    const int*   ind    = (const int*)  d_in[1]; // (128,8,1)
    const float* target = (const float*)d_in[2]; // (128,8,4)
    float*       dst    = (float*)d_out;         // (128,8,72,72)

    const int B = 128 * 8;
    iou_label_kernel<<<B, 128, 0, stream>>>(outp, ind, target, dst);
}

// Round 2
// 115.330 us; speedup vs baseline: 1.0047x; 1.0047x over previous
//
#include <hip/hip_runtime.h>

// Problem constants (from reference): NI=128, NS=8, D=4, W=H=72, RADIUS=5
#define WDIM 72
#define WH   (72 * 72)       // 5184
#define RAD  5
#define NOFF 121             // (2R+1)^2

// One block per batch element b (B = NI*NS = 1024), 256 threads (4 waves).
// Phase 1: fill this b's output plane (5184 floats) with -1.0 via float4
//          (1296 float4 stores -> ~5 iterations/thread).
// Phase 2: lanes 0..120 each own one (rw, rh) offset. The JAX scan writes
// offsets in order t = (rw+5)*11 + (rh+5), last-write-wins on collisions
// (which only occur under clipping). Since clipped cw depends only on rw and
// clipped ch only on rh, the winning lane for a cell is exactly the lane with
// the largest rw mapping to its cw AND largest rh mapping to its ch:
//   win_axis = (r == RAD) || (0 <= c + r <= WDIM-2)
// (if c+r >= WDIM-1, the next r clips to the same WDIM-1; if c+r <= -1, the
//  next r clips to the same 0). Winners have unique cells -> no race.
__global__ __launch_bounds__(256) void iou_label_kernel(
    const float* __restrict__ outp,   // (B, 4, 72, 72)
    const int*   __restrict__ ind,    // (B,)
    const float* __restrict__ target, // (B, 4)
    float*       __restrict__ dst)    // (B, 72, 72)
{
    const int b = blockIdx.x;
    const int t = threadIdx.x;

    float* plane = dst + (size_t)b * WH;

    // Load scatter inputs early (hide latency under the fill).
    const int   idx = ind[b];
    const float4 tg = *reinterpret_cast<const float4*>(target + (size_t)b * 4);

    // ---- Phase 1: fill plane with -1.0f (1296 float4 stores / block) ----
    const float4 neg1 = make_float4(-1.f, -1.f, -1.f, -1.f);
    float4* p4 = reinterpret_cast<float4*>(plane);
    #pragma unroll
    for (int i = t; i < WH / 4; i += 256) p4[i] = neg1;
    __syncthreads();

    // ---- Phase 2: scatter IoU for winning offsets ----
    if (t >= NOFF) return;

    const int rw = t / 11 - RAD;   // slow index (matches jnp.repeat)
    const int rh = t % 11 - RAD;   // fast index (matches jnp.tile)

    const int cw = idx % WDIM;
    const int ch = idx / WDIM;

    const int hh = ch + rh;
    const int ww = cw + rw;
    const bool winh = (rh == RAD) || (hh >= 0 && hh <= WDIM - 2);
    const bool winw = (rw == RAD) || (ww >= 0 && ww <= WDIM - 2);
    if (!(winh && winw)) return;

    const int chc = min(max(hh, 0), WDIM - 1);
    const int cwc = min(max(ww, 0), WDIM - 1);
    const int ic  = chc * WDIM + cwc;

    // pred[d] = outp[b, d, chc, cwc]  (stride WH between d-planes)
    const float* ob = outp + (size_t)b * 4 * WH + ic;
    const float pl = ob[0 * WH];
    const float pr = ob[1 * WH];
    const float pt = ob[2 * WH];
    const float pb = ob[3 * WH];

    const float frw = (float)rw, frh = (float)rh;
    const float tl = tg.x + frw;
    const float tr = tg.y - frw;
    const float tt = tg.z + frh;
    const float tb = tg.w - frh;

    const float inter = (fminf(pl, tl) + fminf(pr, tr)) *
                        (fminf(pb, tb) + fminf(pt, tt));
    const float uni   = (tl + tr) * (tt + tb) + (pl + pr) * (pt + pb) - inter;

    plane[ic] = (inter + 1.0f) / (uni + 1.0f);
}

extern "C" void kernel_launch(void* const* d_in, const int* in_sizes, int n_in,
                              void* d_out, int out_size, void* d_ws, size_t ws_size,
                              hipStream_t stream) {
    const float* outp   = (const float*)d_in[0]; // (128,8,4,72,72)
    const int*   ind    = (const int*)  d_in[1]; // (128,8,1)
    const float* target = (const float*)d_in[2]; // (128,8,4)
    float*       dst    = (float*)d_out;         // (128,8,72,72)

    const int B = 128 * 8;
    iou_label_kernel<<<B, 256, 0, stream>>>(outp, ind, target, dst);
}